// Round 2
// baseline (388.384 us; speedup 1.0000x reference)
//
#include <hip/hip_runtime.h>
#include <hip/hip_bf16.h>

typedef unsigned short u16;
typedef unsigned int u32;
typedef short short8 __attribute__((ext_vector_type(8)));
typedef float f32x4 __attribute__((ext_vector_type(4)));

#define OUTD 7
#define NROI 1024
#define CH 256
#define KDIM 12544   // 256*49
#define NHID 1024
#define KSPLIT 14    // 12544 = 14 * 896 = 14 * (14*64)

__device__ __forceinline__ float bf_lo(u32 u) {
    union { u32 i; float f; } v; v.i = u << 16; return v.f;
}
__device__ __forceinline__ float bf_hi(u32 u) {
    union { u32 i; float f; } v; v.i = u & 0xffff0000u; return v.f;
}
__device__ __forceinline__ u16 f2b(float f) {
    return (u16)(__bfloat16_as_ushort(__float2bfloat16(f)));
}
__device__ __forceinline__ void async16(const void* g, void* l) {
    __builtin_amdgcn_global_load_lds((const __attribute__((address_space(1))) u32*)g,
                                     (__attribute__((address_space(3))) u32*)l, 16, 0, 0);
}

// ---------------- fused prep: feat transpose + w1 transpose + w2 transpose ----------------
// blocks [0,2048): features (B,C,H,W) fp32 -> featT (B,H,W,C) bf16
// blocks [2048,5184): w1 (K,N) fp32 -> w1t (N,K) bf16
// blocks [5184,5233): w2 (K,49) fp32 -> w2t (49,K) fp32
__global__ __launch_bounds__(256) void prep(const float* __restrict__ f,
                                            const float* __restrict__ w1,
                                            const float* __restrict__ w2,
                                            u16* __restrict__ ft,
                                            u16* __restrict__ w1t,
                                            float* __restrict__ w2t) {
    __shared__ u32 smem[64 * 133];
    int bid = blockIdx.x;
    int tid = threadIdx.x;
    if (bid < 2048) {
        // 64 px x 256 ch per block. Reads 256B contiguous chunks; writes fully
        // coalesced 512B per wave. LDS stride 133 u32 (odd) -> conflict-free.
        int pb = bid >> 1;           // 0..1023
        int b  = bid & 1;            // 0..1
        const float* src = f + (size_t)b * CH * 65536 + (size_t)pb * 64;
#pragma unroll
        for (int it = 0; it < 8; ++it) {
            int id = tid + 256 * it;         // 0..2047
            int f4 = id & 15, c2 = id >> 4;  // f4: px-quad, c2: channel pair 0..127
            const float* s0 = src + (size_t)(2 * c2) * 65536 + f4 * 4;
            float4 a = *(const float4*)(s0);
            float4 bb = *(const float4*)(s0 + 65536);
#pragma unroll
            for (int j = 0; j < 4; ++j) {
                float av = (&a.x)[j], bv = (&bb.x)[j];
                smem[(f4 * 4 + j) * 133 + c2] = (u32)f2b(av) | ((u32)f2b(bv) << 16);
            }
        }
        __syncthreads();
        u16* dst = ft + ((size_t)b * 65536 + (size_t)pb * 64) * CH;
#pragma unroll
        for (int it = 0; it < 16; ++it) {
            int px = it * 4 + (tid >> 6);
            int cg = tid & 63;               // 4 channels per thread
            uint2 o;
            o.x = smem[px * 133 + cg * 2];
            o.y = smem[px * 133 + cg * 2 + 1];
            *(uint2*)(dst + (size_t)px * CH + cg * 4) = o;
        }
    } else if (bid < 5184) {
        int t = bid - 2048;                  // 0..3135
        int kb = t % 98, nb = t / 98;        // kb 0..97, nb 0..31
        float (*tile)[129] = (float(*)[129])smem;   // [n][k], 16.5KB < 34KB
#pragma unroll
        for (int i = 0; i < 4; ++i) {
            int id = tid + 256 * i;
            int r = id >> 3, f4 = id & 7;
            float4 v = *(const float4*)(w1 + (size_t)(kb * 128 + r) * NHID + nb * 32 + f4 * 4);
            tile[f4 * 4 + 0][r] = v.x;
            tile[f4 * 4 + 1][r] = v.y;
            tile[f4 * 4 + 2][r] = v.z;
            tile[f4 * 4 + 3][r] = v.w;
        }
        __syncthreads();
#pragma unroll
        for (int i = 0; i < 4; ++i) {
            int id = tid + 256 * i;
            int nn = id >> 5, kg = id & 31;
            uint2 o;
            o.x = (u32)f2b(tile[nn][kg * 4 + 0]) | ((u32)f2b(tile[nn][kg * 4 + 1]) << 16);
            o.y = (u32)f2b(tile[nn][kg * 4 + 2]) | ((u32)f2b(tile[nn][kg * 4 + 3]) << 16);
            *(uint2*)(w1t + (size_t)(nb * 32 + nn) * KDIM + kb * 128 + kg * 4) = o;
        }
    } else {
        int j = bid - 5184;                  // 0..48
        for (int k = tid; k < NHID; k += 256)
            w2t[(size_t)j * NHID + k] = w2[(size_t)k * 49 + j];
    }
}

// ---------------- rotated RoI align: featT -> flat (bf16) ----------------
__global__ __launch_bounds__(256) void roi_align(const u16* __restrict__ ft,
                                                 const float* __restrict__ rois,
                                                 u16* __restrict__ flat) {
    __shared__ u16 sbuf[49 * 260];   // [bin][c], pad 260 keeps uint2 alignment; 25480 B
    int i = blockIdx.x;
    int tid = threadIdx.x;
    int lane = tid & 63, w = tid >> 6;
    float r0 = rois[i * 6 + 0], r1 = rois[i * 6 + 1], r2 = rois[i * 6 + 2];
    float r3 = rois[i * 6 + 3], r4 = rois[i * 6 + 4], th = rois[i * 6 + 5];
    int b = (int)r0;
    float cx = r1 * 0.125f, cy = r2 * 0.125f;
    float rw = fmaxf(r3 * 0.125f, 1.0f), rh = fmaxf(r4 * 0.125f, 1.0f);
    float bw = rw * (1.0f / 7.0f), bh = rh * (1.0f / 7.0f);
    float ct = cosf(th), st = sinf(th);
    const u16* fb = ft + (size_t)b * 65536 * CH;
    int coff = lane * 4;

    int start = w * 12 + (w > 0 ? 1 : 0);
    int cnt = (w == 0) ? 13 : 12;
    for (int bi = 0; bi < cnt; ++bi) {
        int bin = start + bi;
        int ph = bin / 7, pw = bin - ph * 7;
        float a0 = 0.f, a1 = 0.f, a2 = 0.f, a3 = 0.f;
#pragma unroll
        for (int s = 0; s < 4; ++s) {
            int sy = s >> 1, sx2 = s & 1;
            float yy = -rh * 0.5f + ((float)ph + ((float)sy + 0.5f) * 0.5f) * bh;
            float xx = -rw * 0.5f + ((float)pw + ((float)sx2 + 0.5f) * 0.5f) * bw;
            float xs = xx * ct - yy * st + cx;
            float ys = xx * st + yy * ct + cy;
            bool valid = (ys > -1.0f) && (ys < 256.0f) && (xs > -1.0f) && (xs < 256.0f);
            float ysc = fminf(fmaxf(ys, 0.f), 255.f);
            float xsc = fminf(fmaxf(xs, 0.f), 255.f);
            int yl = (int)floorf(ysc), xl = (int)floorf(xsc);
            int yh = min(yl + 1, 255), xh = min(xl + 1, 255);
            float ly = ysc - (float)yl, lx = xsc - (float)xl;
            float hy = 1.f - ly, hx = 1.f - lx;
            float w11 = hy * hx, w12 = hy * lx, w21 = ly * hx, w22 = ly * lx;
            if (!valid) { w11 = w12 = w21 = w22 = 0.f; }
            uint2 v11 = *(const uint2*)(fb + (((size_t)yl * 256 + xl) << 8) + coff);
            uint2 v12 = *(const uint2*)(fb + (((size_t)yl * 256 + xh) << 8) + coff);
            uint2 v21 = *(const uint2*)(fb + (((size_t)yh * 256 + xl) << 8) + coff);
            uint2 v22 = *(const uint2*)(fb + (((size_t)yh * 256 + xh) << 8) + coff);
            a0 += w11 * bf_lo(v11.x) + w12 * bf_lo(v12.x) + w21 * bf_lo(v21.x) + w22 * bf_lo(v22.x);
            a1 += w11 * bf_hi(v11.x) + w12 * bf_hi(v12.x) + w21 * bf_hi(v21.x) + w22 * bf_hi(v22.x);
            a2 += w11 * bf_lo(v11.y) + w12 * bf_lo(v12.y) + w21 * bf_lo(v21.y) + w22 * bf_lo(v22.y);
            a3 += w11 * bf_hi(v11.y) + w12 * bf_hi(v12.y) + w21 * bf_hi(v21.y) + w22 * bf_hi(v22.y);
        }
        uint2 o;
        o.x = (u32)f2b(a0 * 0.25f) | ((u32)f2b(a1 * 0.25f) << 16);
        o.y = (u32)f2b(a2 * 0.25f) | ((u32)f2b(a3 * 0.25f) << 16);
        *(uint2*)(sbuf + bin * 260 + coff) = o;
    }
    __syncthreads();
    // write flat[i][c*49+bin], 4 elems/thread/iter, coalesced uint2 stores
    uint2* fl = (uint2*)(flat + (size_t)i * KDIM);
#pragma unroll 1
    for (int k = tid; k < 3136; k += 256) {
        int e = k * 4;
        int c = e / 49, bn = e - c * 49;
        u16 r0_ = sbuf[bn * 260 + c]; if (++bn == 49) { bn = 0; ++c; }
        u16 r1_ = sbuf[bn * 260 + c]; if (++bn == 49) { bn = 0; ++c; }
        u16 r2_ = sbuf[bn * 260 + c]; if (++bn == 49) { bn = 0; ++c; }
        u16 r3_ = sbuf[bn * 260 + c];
        uint2 o;
        o.x = (u32)r0_ | ((u32)r1_ << 16);
        o.y = (u32)r2_ | ((u32)r3_ << 16);
        fl[k] = o;
    }
}

// ---------------- GEMM1: flat[1024,12544]bf16 @ w1t[1024,12544]^T -> part fp32 ----------------
// 256x256 tile, 8 waves (2Mx4N), BK=64, KSPLIT=14 (K-run = 14*64 = 896 exactly).
// Staged traffic: A read x4 + B read x4 = 206MB (was 411MB at 128^2).
// 2-phase double-buffer: prefetch slice s+1 via global_load_lds during MFMA on s;
// counted s_waitcnt vmcnt(8) keeps the prefetch in flight across the barrier.
// XOR-8 swizzle applied on the GLOBAL side (global_load_lds dest must be linear).
__global__ __launch_bounds__(512) void gemm1(const u16* __restrict__ A,
                                             const u16* __restrict__ Bt,
                                             float* __restrict__ part) {
    const int K = KDIM;
    int nb = blockIdx.x, mb = blockIdx.y, ks = blockIdx.z;
    const int steps = 14;
    int kbase = ks * 896;
    __shared__ __align__(16) u16 As[2][256 * 64];   // 64KB
    __shared__ __align__(16) u16 Bs[2][256 * 64];   // 64KB
    int tid = threadIdx.x;
    int lane = tid & 63, w = tid >> 6;   // w 0..7
    int wm = w >> 2, wn = w & 3;         // wave grid 2M x 4N; wave tile 128x64
    f32x4 acc[8][4] = {};
    const u16* Ab = A + (size_t)(mb * 256) * K;
    const u16* Bb = Bt + (size_t)(nb * 256) * K;

    // stage: 32 wave-chunks of 1KB each for A and B; lane L of chunk c lands at
    // LDS c*512 + L*8 (u16) == row*64 + pq*8 with row=c*8+(L>>3), pq=L&7.
    auto stage = [&](int buf, int kk) {
#pragma unroll
        for (int j = 0; j < 4; ++j) {
            int c = w * 4 + j;                 // 0..31
            int cid = c * 64 + lane;           // 0..2047
            int row = cid >> 3, pq = cid & 7;  // row 0..255
            int q = pq ^ (row & 7);            // global-side swizzle
            async16(Ab + (size_t)row * K + kk + q * 8, &As[buf][c * 512 + lane * 8]);
            async16(Bb + (size_t)row * K + kk + q * 8, &Bs[buf][c * 512 + lane * 8]);
        }
    };

    stage(0, kbase);
    int cur = 0;
    for (int s = 0; s < steps; ++s) {
        if (s + 1 < steps) {
            stage(cur ^ 1, kbase + (s + 1) * 64);            // 8 new loads in flight
            asm volatile("s_waitcnt vmcnt(8)" ::: "memory"); // own cur-buffer loads done
        } else {
            asm volatile("s_waitcnt vmcnt(0)" ::: "memory");
        }
        __builtin_amdgcn_s_barrier();                        // all waves' cur-buffer done
        const u16* Asb = &As[cur][0];
        const u16* Bsb = &Bs[cur][0];
#pragma unroll
        for (int kh = 0; kh < 2; ++kh) {
            short8 af[8], bf[4];
            int q = kh * 4 + (lane >> 4);
#pragma unroll
            for (int t = 0; t < 8; ++t) {
                int r = wm * 128 + t * 16 + (lane & 15);
                int pq = q ^ (r & 7);
                af[t] = *(const short8*)(Asb + r * 64 + pq * 8);
            }
#pragma unroll
            for (int t = 0; t < 4; ++t) {
                int rb = wn * 64 + t * 16 + (lane & 15);
                int pqb = q ^ (rb & 7);
                bf[t] = *(const short8*)(Bsb + rb * 64 + pqb * 8);
            }
#pragma unroll
            for (int mt = 0; mt < 8; ++mt)
#pragma unroll
                for (int nt = 0; nt < 4; ++nt)
                    acc[mt][nt] = __builtin_amdgcn_mfma_f32_16x16x32_bf16(af[mt], bf[nt], acc[mt][nt], 0, 0, 0);
        }
        __builtin_amdgcn_s_barrier();                        // reads of cur done before overwrite
        cur ^= 1;
    }
    float* P = part + (size_t)ks * NROI * NHID;
    int m_base = mb * 256 + wm * 128, n_base = nb * 256 + wn * 64;
#pragma unroll
    for (int mt = 0; mt < 8; ++mt)
#pragma unroll
        for (int nt = 0; nt < 4; ++nt)
#pragma unroll
            for (int i = 0; i < 4; ++i) {
                int m = m_base + mt * 16 + (lane >> 4) * 4 + i;
                int n = n_base + nt * 16 + (lane & 15);
                P[(size_t)m * NHID + n] = acc[mt][nt][i];
            }
}

// ---------------- fused: split-K reduce + bias + relu + GEMM2 + sigmoid + apply ----------------
__global__ __launch_bounds__(256) void gemm2_apply(const float* __restrict__ part,
                                                   const float* __restrict__ b1,
                                                   const float* __restrict__ w2t,
                                                   const float* __restrict__ b2,
                                                   const u16* __restrict__ flat,
                                                   float* __restrict__ out) {
    __shared__ __align__(16) float hrow[NHID];
    __shared__ float partial[256];
    __shared__ float mrow[49];
    int i = blockIdx.x;
    int tid = threadIdx.x;
    // reduce split-K partials for this roi's hid row + bias + relu, into LDS
    {
        float4 s = ((const float4*)b1)[tid];
        size_t base = (size_t)i * 256 + tid;   // float4 index within one K-slice
#pragma unroll
        for (int j = 0; j < KSPLIT; ++j) {
            float4 p = ((const float4*)part)[(size_t)j * 262144 + base];
            s.x += p.x; s.y += p.y; s.z += p.z; s.w += p.w;
        }
        float4 r;
        r.x = fmaxf(s.x, 0.f); r.y = fmaxf(s.y, 0.f);
        r.z = fmaxf(s.z, 0.f); r.w = fmaxf(s.w, 0.f);
        ((float4*)hrow)[tid] = r;
    }
    __syncthreads();
    float p = 0.f;
    if (tid < 245) {
        int j = tid / 5, kc = tid - (tid / 5) * 5;
        int k0 = (256 * kc) / 5, k1 = (256 * (kc + 1)) / 5;   // float4 chunks
        const float4* wv = (const float4*)(w2t + (size_t)j * NHID);
        const float4* hv = (const float4*)hrow;
        for (int k = k0; k < k1; ++k) {
            float4 a = hv[k], b = wv[k];
            p += a.x * b.x + a.y * b.y + a.z * b.z + a.w * b.w;
        }
    }
    partial[tid] = p;
    __syncthreads();
    if (tid < 49) {
        float s = b2[tid];
#pragma unroll
        for (int q = 0; q < 5; ++q) s += partial[tid * 5 + q];
        mrow[tid] = 1.f / (1.f + expf(-s));
    }
    __syncthreads();
    const uint2* fl = (const uint2*)(flat + (size_t)i * KDIM);
    float4* op = (float4*)(out + (size_t)i * KDIM);
#pragma unroll 1
    for (int idx = tid; idx < 3136; idx += 256) {
        uint2 v = fl[idx];
        int e = idx * 4;
        int pp = e - (e / 49) * 49;
        float4 r;
        r.x = bf_lo(v.x) * mrow[pp]; if (++pp == 49) pp = 0;
        r.y = bf_hi(v.x) * mrow[pp]; if (++pp == 49) pp = 0;
        r.z = bf_lo(v.y) * mrow[pp]; if (++pp == 49) pp = 0;
        r.w = bf_hi(v.y) * mrow[pp];
        op[idx] = r;
    }
}

extern "C" void kernel_launch(void* const* d_in, const int* in_sizes, int n_in,
                              void* d_out, int out_size, void* d_ws, size_t ws_size,
                              hipStream_t stream) {
    const float* features = (const float*)d_in[0];
    const float* rois     = (const float*)d_in[1];
    const float* w1       = (const float*)d_in[2];
    const float* b1       = (const float*)d_in[3];
    const float* w2       = (const float*)d_in[4];
    const float* b2       = (const float*)d_in[5];
    float* out = (float*)d_out;
    char* ws = (char*)d_ws;

    u16* featT  = (u16*)(ws);                      // 67,108,864
    u16* flat   = (u16*)(ws + 67108864);           // 25,690,112
    u16* w1t    = (u16*)(ws + 92798976);           // 25,690,112
    float* part = (float*)(ws + 118489088);        // 58,720,256 (KSPLIT=14)
    float* w2t  = (float*)(ws + 177209344);        // 200,704

    prep<<<5233, 256, 0, stream>>>(features, w1, w2, featT, w1t, w2t);
    roi_align<<<NROI, 256, 0, stream>>>(featT, rois, flat);
    gemm1<<<dim3(4, 4, KSPLIT), 512, 0, stream>>>(flat, w1t, part);
    gemm2_apply<<<NROI, 256, 0, stream>>>(part, b1, w2t, b2, flat, out);
}

// Round 3
// 387.786 us; speedup vs baseline: 1.0015x; 1.0015x over previous
//
#include <hip/hip_runtime.h>
#include <hip/hip_bf16.h>

typedef unsigned short u16;
typedef unsigned int u32;
typedef short short8 __attribute__((ext_vector_type(8)));
typedef float f32x4 __attribute__((ext_vector_type(4)));

#define OUTD 7
#define NROI 1024
#define CH 256
#define KDIM 12544   // 256*49
#define NHID 1024
#define KSPLIT 14    // 12544 = 14 * 896 = 14 * (14*64)

__device__ __forceinline__ float bf_lo(u32 u) {
    union { u32 i; float f; } v; v.i = u << 16; return v.f;
}
__device__ __forceinline__ float bf_hi(u32 u) {
    union { u32 i; float f; } v; v.i = u & 0xffff0000u; return v.f;
}
__device__ __forceinline__ u16 f2b(float f) {
    return (u16)(__bfloat16_as_ushort(__float2bfloat16(f)));
}
__device__ __forceinline__ void async16(const void* g, void* l) {
    __builtin_amdgcn_global_load_lds((const __attribute__((address_space(1))) u32*)g,
                                     (__attribute__((address_space(3))) u32*)l, 16, 0, 0);
}

// ---------------- fused prep: feat transpose + w1 transpose + w2 transpose ----------------
// blocks [0,2048): features (B,C,H,W) fp32 -> featT (B,H,W,C) bf16
//   256 px x 64 ch per block; 16-load register burst (latency hiding: 16 loads in
//   flight/wave x 16 waves/CU = 4KB/CU outstanding vs 2.8KB before); 1KB-contiguous
//   reads per channel plane; XOR-swizzled 32KB LDS (read side conflict-free).
// blocks [2048,5184): w1 (K,N) fp32 -> w1t (N,K) bf16 (4-load burst)
// blocks [5184,5233): w2 (K,49) fp32 -> w2t (49,K) fp32
__global__ __launch_bounds__(256, 4) void prep(const float* __restrict__ f,
                                               const float* __restrict__ w1,
                                               const float* __restrict__ w2,
                                               u16* __restrict__ ft,
                                               u16* __restrict__ w1t,
                                               float* __restrict__ w2t) {
    __shared__ u32 smem[256 * 32];   // 32 KB
    int bid = blockIdx.x;
    int tid = threadIdx.x;
    if (bid < 2048) {
        int pb = bid & 255;          // px block 0..255 (256 px each)
        int cb = (bid >> 8) & 3;     // channel block 0..3 (64 ch each)
        int b  = bid >> 10;          // 0..1
        const float* src = f + ((size_t)(b * CH + cb * 64)) * 65536 + (size_t)pb * 256;
        // burst-load 16 float4 (8 iters x 2 adjacent channels) into registers
        float4 ra[8], rb[8];
#pragma unroll
        for (int it = 0; it < 8; ++it) {
            int id = tid + 256 * it;         // 0..2047
            int px4 = id & 63, c2 = id >> 6; // px-quad 0..63 (wave-varying), c2 0..31 (wave-uniform)
            const float* s0 = src + (size_t)(2 * c2) * 65536 + px4 * 4;
            ra[it] = *(const float4*)(s0);
            rb[it] = *(const float4*)(s0 + 65536);
        }
        // convert + swizzled LDS store: word (px, c2) at [px*32 + (c2 ^ s(px))]
#pragma unroll
        for (int it = 0; it < 8; ++it) {
            int id = tid + 256 * it;
            int px4 = id & 63, c2 = id >> 6;
#pragma unroll
            for (int j = 0; j < 4; ++j) {
                int px = px4 * 4 + j;
                int s = ((px >> 2) & 15) << 1;           // even -> uint2 pairing preserved
                smem[px * 32 + (c2 ^ s)] =
                    (u32)f2b((&ra[it].x)[j]) | ((u32)f2b((&rb[it].x)[j]) << 16);
            }
        }
        __syncthreads();
        // write: 4 px x 128B contiguous segments per wave-instr, fully-lined
        u16* dst = ft + ((size_t)b * 65536 + (size_t)pb * 256) * CH + cb * 64;
#pragma unroll
        for (int it = 0; it < 16; ++it) {
            int cg = tid & 15;                   // uint2 index within 64-ch row
            int px = (tid >> 4) + 16 * it;       // 0..255
            int s = ((px >> 2) & 15) << 1;
            int base = px * 32 + ((2 * cg) ^ s); // even -> aligned uint2
            uint2 o;
            o.x = smem[base];
            o.y = smem[base + 1];
            *(uint2*)(dst + (size_t)px * CH + cg * 4) = o;
        }
    } else if (bid < 5184) {
        int t = bid - 2048;                  // 0..3135
        int kb = t % 98, nb = t / 98;        // kb 0..97, nb 0..31
        float (*tile)[129] = (float(*)[129])smem;   // [n][k], 16.5KB < 32KB
        float4 v[4];
#pragma unroll
        for (int i = 0; i < 4; ++i) {
            int id = tid + 256 * i;
            int r = id >> 3, f4 = id & 7;
            v[i] = *(const float4*)(w1 + (size_t)(kb * 128 + r) * NHID + nb * 32 + f4 * 4);
        }
#pragma unroll
        for (int i = 0; i < 4; ++i) {
            int id = tid + 256 * i;
            int r = id >> 3, f4 = id & 7;
            tile[f4 * 4 + 0][r] = v[i].x;
            tile[f4 * 4 + 1][r] = v[i].y;
            tile[f4 * 4 + 2][r] = v[i].z;
            tile[f4 * 4 + 3][r] = v[i].w;
        }
        __syncthreads();
#pragma unroll
        for (int i = 0; i < 4; ++i) {
            int id = tid + 256 * i;
            int nn = id >> 5, kg = id & 31;
            uint2 o;
            o.x = (u32)f2b(tile[nn][kg * 4 + 0]) | ((u32)f2b(tile[nn][kg * 4 + 1]) << 16);
            o.y = (u32)f2b(tile[nn][kg * 4 + 2]) | ((u32)f2b(tile[nn][kg * 4 + 3]) << 16);
            *(uint2*)(w1t + (size_t)(nb * 32 + nn) * KDIM + kb * 128 + kg * 4) = o;
        }
    } else {
        int j = bid - 5184;                  // 0..48
        for (int k = tid; k < NHID; k += 256)
            w2t[(size_t)j * NHID + k] = w2[(size_t)k * 49 + j];
    }
}

// ---------------- rotated RoI align: featT -> flat (bf16) ----------------
__global__ __launch_bounds__(256) void roi_align(const u16* __restrict__ ft,
                                                 const float* __restrict__ rois,
                                                 u16* __restrict__ flat) {
    __shared__ u16 sbuf[49 * 260];   // [bin][c], pad 260 keeps uint2 alignment; 25480 B
    int i = blockIdx.x;
    int tid = threadIdx.x;
    int lane = tid & 63, w = tid >> 6;
    float r0 = rois[i * 6 + 0], r1 = rois[i * 6 + 1], r2 = rois[i * 6 + 2];
    float r3 = rois[i * 6 + 3], r4 = rois[i * 6 + 4], th = rois[i * 6 + 5];
    int b = (int)r0;
    float cx = r1 * 0.125f, cy = r2 * 0.125f;
    float rw = fmaxf(r3 * 0.125f, 1.0f), rh = fmaxf(r4 * 0.125f, 1.0f);
    float bw = rw * (1.0f / 7.0f), bh = rh * (1.0f / 7.0f);
    float ct = cosf(th), st = sinf(th);
    const u16* fb = ft + (size_t)b * 65536 * CH;
    int coff = lane * 4;

    int start = w * 12 + (w > 0 ? 1 : 0);
    int cnt = (w == 0) ? 13 : 12;
    for (int bi = 0; bi < cnt; ++bi) {
        int bin = start + bi;
        int ph = bin / 7, pw = bin - ph * 7;
        float a0 = 0.f, a1 = 0.f, a2 = 0.f, a3 = 0.f;
#pragma unroll
        for (int s = 0; s < 4; ++s) {
            int sy = s >> 1, sx2 = s & 1;
            float yy = -rh * 0.5f + ((float)ph + ((float)sy + 0.5f) * 0.5f) * bh;
            float xx = -rw * 0.5f + ((float)pw + ((float)sx2 + 0.5f) * 0.5f) * bw;
            float xs = xx * ct - yy * st + cx;
            float ys = xx * st + yy * ct + cy;
            bool valid = (ys > -1.0f) && (ys < 256.0f) && (xs > -1.0f) && (xs < 256.0f);
            float ysc = fminf(fmaxf(ys, 0.f), 255.f);
            float xsc = fminf(fmaxf(xs, 0.f), 255.f);
            int yl = (int)floorf(ysc), xl = (int)floorf(xsc);
            int yh = min(yl + 1, 255), xh = min(xl + 1, 255);
            float ly = ysc - (float)yl, lx = xsc - (float)xl;
            float hy = 1.f - ly, hx = 1.f - lx;
            float w11 = hy * hx, w12 = hy * lx, w21 = ly * hx, w22 = ly * lx;
            if (!valid) { w11 = w12 = w21 = w22 = 0.f; }
            uint2 v11 = *(const uint2*)(fb + (((size_t)yl * 256 + xl) << 8) + coff);
            uint2 v12 = *(const uint2*)(fb + (((size_t)yl * 256 + xh) << 8) + coff);
            uint2 v21 = *(const uint2*)(fb + (((size_t)yh * 256 + xl) << 8) + coff);
            uint2 v22 = *(const uint2*)(fb + (((size_t)yh * 256 + xh) << 8) + coff);
            a0 += w11 * bf_lo(v11.x) + w12 * bf_lo(v12.x) + w21 * bf_lo(v21.x) + w22 * bf_lo(v22.x);
            a1 += w11 * bf_hi(v11.x) + w12 * bf_hi(v12.x) + w21 * bf_hi(v21.x) + w22 * bf_hi(v22.x);
            a2 += w11 * bf_lo(v11.y) + w12 * bf_lo(v12.y) + w21 * bf_lo(v21.y) + w22 * bf_lo(v22.y);
            a3 += w11 * bf_hi(v11.y) + w12 * bf_hi(v12.y) + w21 * bf_hi(v21.y) + w22 * bf_hi(v22.y);
        }
        uint2 o;
        o.x = (u32)f2b(a0 * 0.25f) | ((u32)f2b(a1 * 0.25f) << 16);
        o.y = (u32)f2b(a2 * 0.25f) | ((u32)f2b(a3 * 0.25f) << 16);
        *(uint2*)(sbuf + bin * 260 + coff) = o;
    }
    __syncthreads();
    // write flat[i][c*49+bin], 4 elems/thread/iter, coalesced uint2 stores
    uint2* fl = (uint2*)(flat + (size_t)i * KDIM);
#pragma unroll 1
    for (int k = tid; k < 3136; k += 256) {
        int e = k * 4;
        int c = e / 49, bn = e - c * 49;
        u16 r0_ = sbuf[bn * 260 + c]; if (++bn == 49) { bn = 0; ++c; }
        u16 r1_ = sbuf[bn * 260 + c]; if (++bn == 49) { bn = 0; ++c; }
        u16 r2_ = sbuf[bn * 260 + c]; if (++bn == 49) { bn = 0; ++c; }
        u16 r3_ = sbuf[bn * 260 + c];
        uint2 o;
        o.x = (u32)r0_ | ((u32)r1_ << 16);
        o.y = (u32)r2_ | ((u32)r3_ << 16);
        fl[k] = o;
    }
}

// ---------------- GEMM1: flat[1024,12544]bf16 @ w1t[1024,12544]^T -> part fp32 ----------------
// 256x256 tile, 8 waves (2Mx4N), BK=64, KSPLIT=14 (K-run = 14*64 = 896 exactly).
// 2-phase double-buffer: prefetch slice s+1 via global_load_lds during MFMA on s;
// counted s_waitcnt vmcnt(8) keeps the prefetch in flight across the barrier.
// XOR-8 swizzle applied on the GLOBAL side (global_load_lds dest must be linear).
__global__ __launch_bounds__(512) void gemm1(const u16* __restrict__ A,
                                             const u16* __restrict__ Bt,
                                             float* __restrict__ part) {
    const int K = KDIM;
    int nb = blockIdx.x, mb = blockIdx.y, ks = blockIdx.z;
    const int steps = 14;
    int kbase = ks * 896;
    __shared__ __align__(16) u16 As[2][256 * 64];   // 64KB
    __shared__ __align__(16) u16 Bs[2][256 * 64];   // 64KB
    int tid = threadIdx.x;
    int lane = tid & 63, w = tid >> 6;   // w 0..7
    int wm = w >> 2, wn = w & 3;         // wave grid 2M x 4N; wave tile 128x64
    f32x4 acc[8][4] = {};
    const u16* Ab = A + (size_t)(mb * 256) * K;
    const u16* Bb = Bt + (size_t)(nb * 256) * K;

    auto stage = [&](int buf, int kk) {
#pragma unroll
        for (int j = 0; j < 4; ++j) {
            int c = w * 4 + j;                 // 0..31
            int cid = c * 64 + lane;           // 0..2047
            int row = cid >> 3, pq = cid & 7;  // row 0..255
            int q = pq ^ (row & 7);            // global-side swizzle
            async16(Ab + (size_t)row * K + kk + q * 8, &As[buf][c * 512 + lane * 8]);
            async16(Bb + (size_t)row * K + kk + q * 8, &Bs[buf][c * 512 + lane * 8]);
        }
    };

    stage(0, kbase);
    int cur = 0;
    for (int s = 0; s < steps; ++s) {
        if (s + 1 < steps) {
            stage(cur ^ 1, kbase + (s + 1) * 64);            // 8 new loads in flight
            asm volatile("s_waitcnt vmcnt(8)" ::: "memory"); // own cur-buffer loads done
        } else {
            asm volatile("s_waitcnt vmcnt(0)" ::: "memory");
        }
        __builtin_amdgcn_s_barrier();                        // all waves' cur-buffer done
        const u16* Asb = &As[cur][0];
        const u16* Bsb = &Bs[cur][0];
#pragma unroll
        for (int kh = 0; kh < 2; ++kh) {
            short8 af[8], bf[4];
            int q = kh * 4 + (lane >> 4);
#pragma unroll
            for (int t = 0; t < 8; ++t) {
                int r = wm * 128 + t * 16 + (lane & 15);
                int pq = q ^ (r & 7);
                af[t] = *(const short8*)(Asb + r * 64 + pq * 8);
            }
#pragma unroll
            for (int t = 0; t < 4; ++t) {
                int rb = wn * 64 + t * 16 + (lane & 15);
                int pqb = q ^ (rb & 7);
                bf[t] = *(const short8*)(Bsb + rb * 64 + pqb * 8);
            }
#pragma unroll
            for (int mt = 0; mt < 8; ++mt)
#pragma unroll
                for (int nt = 0; nt < 4; ++nt)
                    acc[mt][nt] = __builtin_amdgcn_mfma_f32_16x16x32_bf16(af[mt], bf[nt], acc[mt][nt], 0, 0, 0);
        }
        __builtin_amdgcn_s_barrier();                        // reads of cur done before overwrite
        cur ^= 1;
    }
    float* P = part + (size_t)ks * NROI * NHID;
    int m_base = mb * 256 + wm * 128, n_base = nb * 256 + wn * 64;
#pragma unroll
    for (int mt = 0; mt < 8; ++mt)
#pragma unroll
        for (int nt = 0; nt < 4; ++nt)
#pragma unroll
            for (int i = 0; i < 4; ++i) {
                int m = m_base + mt * 16 + (lane >> 4) * 4 + i;
                int n = n_base + nt * 16 + (lane & 15);
                P[(size_t)m * NHID + n] = acc[mt][nt][i];
            }
}

// ---------------- fused: split-K reduce + bias + relu + GEMM2 + sigmoid + apply ----------------
__global__ __launch_bounds__(256) void gemm2_apply(const float* __restrict__ part,
                                                   const float* __restrict__ b1,
                                                   const float* __restrict__ w2t,
                                                   const float* __restrict__ b2,
                                                   const u16* __restrict__ flat,
                                                   float* __restrict__ out) {
    __shared__ __align__(16) float hrow[NHID];
    __shared__ float partial[256];
    __shared__ float mrow[49];
    int i = blockIdx.x;
    int tid = threadIdx.x;
    // reduce split-K partials for this roi's hid row + bias + relu, into LDS
    {
        float4 s = ((const float4*)b1)[tid];
        size_t base = (size_t)i * 256 + tid;   // float4 index within one K-slice
#pragma unroll
        for (int j = 0; j < KSPLIT; ++j) {
            float4 p = ((const float4*)part)[(size_t)j * 262144 + base];
            s.x += p.x; s.y += p.y; s.z += p.z; s.w += p.w;
        }
        float4 r;
        r.x = fmaxf(s.x, 0.f); r.y = fmaxf(s.y, 0.f);
        r.z = fmaxf(s.z, 0.f); r.w = fmaxf(s.w, 0.f);
        ((float4*)hrow)[tid] = r;
    }
    __syncthreads();
    float p = 0.f;
    if (tid < 245) {
        int j = tid / 5, kc = tid - (tid / 5) * 5;
        int k0 = (256 * kc) / 5, k1 = (256 * (kc + 1)) / 5;   // float4 chunks
        const float4* wv = (const float4*)(w2t + (size_t)j * NHID);
        const float4* hv = (const float4*)hrow;
        for (int k = k0; k < k1; ++k) {
            float4 a = hv[k], b = wv[k];
            p += a.x * b.x + a.y * b.y + a.z * b.z + a.w * b.w;
        }
    }
    partial[tid] = p;
    __syncthreads();
    if (tid < 49) {
        float s = b2[tid];
#pragma unroll
        for (int q = 0; q < 5; ++q) s += partial[tid * 5 + q];
        mrow[tid] = 1.f / (1.f + expf(-s));
    }
    __syncthreads();
    const uint2* fl = (const uint2*)(flat + (size_t)i * KDIM);
    float4* op = (float4*)(out + (size_t)i * KDIM);
#pragma unroll 1
    for (int idx = tid; idx < 3136; idx += 256) {
        uint2 v = fl[idx];
        int e = idx * 4;
        int pp = e - (e / 49) * 49;
        float4 r;
        r.x = bf_lo(v.x) * mrow[pp]; if (++pp == 49) pp = 0;
        r.y = bf_hi(v.x) * mrow[pp]; if (++pp == 49) pp = 0;
        r.z = bf_lo(v.y) * mrow[pp]; if (++pp == 49) pp = 0;
        r.w = bf_hi(v.y) * mrow[pp];
        op[idx] = r;
    }
}

extern "C" void kernel_launch(void* const* d_in, const int* in_sizes, int n_in,
                              void* d_out, int out_size, void* d_ws, size_t ws_size,
                              hipStream_t stream) {
    const float* features = (const float*)d_in[0];
    const float* rois     = (const float*)d_in[1];
    const float* w1       = (const float*)d_in[2];
    const float* b1       = (const float*)d_in[3];
    const float* w2       = (const float*)d_in[4];
    const float* b2       = (const float*)d_in[5];
    float* out = (float*)d_out;
    char* ws = (char*)d_ws;

    u16* featT  = (u16*)(ws);                      // 67,108,864
    u16* flat   = (u16*)(ws + 67108864);           // 25,690,112
    u16* w1t    = (u16*)(ws + 92798976);           // 25,690,112
    float* part = (float*)(ws + 118489088);        // 58,720,256 (KSPLIT=14)
    float* w2t  = (float*)(ws + 177209344);        // 200,704

    prep<<<5233, 256, 0, stream>>>(features, w1, w2, featT, w1t, w2t);
    roi_align<<<NROI, 256, 0, stream>>>(featT, rois, flat);
    gemm1<<<dim3(4, 4, KSPLIT), 512, 0, stream>>>(flat, w1t, part);
    gemm2_apply<<<NROI, 256, 0, stream>>>(part, b1, w2t, b2, flat, out);
}

// Round 4
// 386.522 us; speedup vs baseline: 1.0048x; 1.0033x over previous
//
#include <hip/hip_runtime.h>
#include <hip/hip_bf16.h>

typedef unsigned short u16;
typedef unsigned int u32;
typedef short short8 __attribute__((ext_vector_type(8)));
typedef float f32x4 __attribute__((ext_vector_type(4)));

#define OUTD 7
#define NROI 1024
#define CH 256
#define KDIM 12544   // 256*49
#define NHID 1024
#define KSPLIT 14    // 12544 = 14 * 896 = 14 * (14*64)

__device__ __forceinline__ float bf_lo(u32 u) {
    union { u32 i; float f; } v; v.i = u << 16; return v.f;
}
__device__ __forceinline__ float bf_hi(u32 u) {
    union { u32 i; float f; } v; v.i = u & 0xffff0000u; return v.f;
}
__device__ __forceinline__ u16 f2b(float f) {
    return (u16)(__bfloat16_as_ushort(__float2bfloat16(f)));
}
__device__ __forceinline__ void async16(const void* g, void* l) {
    __builtin_amdgcn_global_load_lds((const __attribute__((address_space(1))) u32*)g,
                                     (__attribute__((address_space(3))) u32*)l, 16, 0, 0);
}

// ---------------- fused prep: feat transpose + w1 transpose + w2 transpose ----------------
// Both transposes use global_load_lds staging (zero VGPR pressure -> 16 loads/wave
// guaranteed in flight; 128KB/CU outstanding vs ~22KB needed for BW saturation).
// XOR swizzle on the GLOBAL source quad (LDS dest must be linear, m104/m173) so the
// ds_read_b128 read-back hits the 8-lanes-per-4-bank-slot conflict-free floor.
// blocks [0,2048): features (B,C,H,W) fp32 -> featT (B,H,W,C) bf16  (256px x 64ch)
// blocks [2048,5184): w1 (K,N) fp32 -> w1t (N,K) bf16               (128k x 32n)
// blocks [5184,5233): w2 (K,49) fp32 -> w2t (49,K) fp32
__global__ __launch_bounds__(256) void prep(const float* __restrict__ f,
                                            const float* __restrict__ w1,
                                            const float* __restrict__ w2,
                                            u16* __restrict__ ft,
                                            u16* __restrict__ w1t,
                                            float* __restrict__ w2t) {
    __shared__ __align__(16) u32 smem[16384];   // 64 KB
    int bid = blockIdx.x;
    int tid = threadIdx.x;
    int lane = tid & 63, w = tid >> 6;
    if (bid < 2048) {
        int pb = bid & 255;          // px block (256 px each)
        int cb = (bid >> 8) & 3;     // channel block (64 ch each)
        int b  = bid >> 10;
        const float* src = f + ((size_t)(b * CH + cb * 64)) * 65536 + (size_t)pb * 256;
        // stage: 64 planes x 1KB. LDS plane p at p*1024B, slot L holds global
        // px-quad (L ^ s(p)), s(p) = (p>>2)&7.
#pragma unroll
        for (int j = 0; j < 16; ++j) {
            int p = w * 16 + j;
            int s = (p >> 2) & 7;
            async16(src + (size_t)p * 65536 + (lane ^ s) * 4,
                    &smem[p * 256 + lane * 4]);
        }
        __syncthreads();
        // read-back: thread = (cg = ch-quad 0..15, Q = px-quad). 4x ds_read_b128
        // (planes 4cg..4cg+3, quad Q) -> 4 px x uint2 (4 ch) stores, 128B/16-lane line.
        int cg = tid & 15, qg = tid >> 4;
        u16* dst = ft + ((size_t)b * 65536 + (size_t)pb * 256) * CH + cb * 64;
#pragma unroll
        for (int it = 0; it < 4; ++it) {
            int Q = qg + 16 * it;
            float4 v[4];
#pragma unroll
            for (int j = 0; j < 4; ++j) {
                int p = 4 * cg + j;                        // s(p) = cg & 7
                v[j] = *(const float4*)&smem[p * 256 + (Q ^ (cg & 7)) * 4];
            }
#pragma unroll
            for (int k = 0; k < 4; ++k) {
                uint2 o;
                o.x = (u32)f2b((&v[0].x)[k]) | ((u32)f2b((&v[1].x)[k]) << 16);
                o.y = (u32)f2b((&v[2].x)[k]) | ((u32)f2b((&v[3].x)[k]) << 16);
                *(uint2*)(dst + (size_t)(4 * Q + k) * CH + cg * 4) = o;
            }
        }
    } else if (bid < 5184) {
        int t = bid - 2048;                  // 0..3135
        int kb = t % 98, nb = t / 98;        // 128 rows x 32 cols of w1
        const float* src = w1 + (size_t)(kb * 128) * NHID + nb * 32;
        // stage: 16 chunks of 8 rows x 128B = 1KB. LDS row r at r*128B, col-quad
        // slot q holds global col-quad (q ^ s(r)), s(r) = (r>>2)&7.
#pragma unroll
        for (int j = 0; j < 4; ++j) {
            int chunk = w * 4 + j;
            int r = chunk * 8 + (lane >> 3);
            int s = (r >> 2) & 7;
            async16(src + (size_t)r * NHID + (((lane & 7) ^ s) * 4),
                    &smem[chunk * 256 + lane * 4]);
        }
        __syncthreads();
        // read-back: thread = (Kq = row-quad 0..31, cqg = col-quad 0..7).
        // 4x ds_read_b128 (rows 4Kq..4Kq+3, col-quad cqg) -> 4 n-rows x uint2(4 k).
        int Kq = tid & 31, cqg = tid >> 5;
        float4 v[4];
#pragma unroll
        for (int j = 0; j < 4; ++j) {
            int r = 4 * Kq + j;                            // s(r) = Kq & 7
            v[j] = *(const float4*)&smem[r * 32 + (cqg ^ (Kq & 7)) * 4];
        }
        u16* dstw = w1t + (size_t)(nb * 32 + cqg * 4) * KDIM + kb * 128 + Kq * 4;
#pragma unroll
        for (int i = 0; i < 4; ++i) {
            uint2 o;
            o.x = (u32)f2b((&v[0].x)[i]) | ((u32)f2b((&v[1].x)[i]) << 16);
            o.y = (u32)f2b((&v[2].x)[i]) | ((u32)f2b((&v[3].x)[i]) << 16);
            *(uint2*)(dstw + (size_t)i * KDIM) = o;
        }
    } else {
        int j = bid - 5184;                  // 0..48
        for (int k = tid; k < NHID; k += 256)
            w2t[(size_t)j * NHID + k] = w2[(size_t)k * 49 + j];
    }
}

// ---------------- rotated RoI align: featT -> flat (bf16) ----------------
__global__ __launch_bounds__(256) void roi_align(const u16* __restrict__ ft,
                                                 const float* __restrict__ rois,
                                                 u16* __restrict__ flat) {
    __shared__ u16 sbuf[49 * 260];   // [bin][c], pad 260 keeps uint2 alignment; 25480 B
    int i = blockIdx.x;
    int tid = threadIdx.x;
    int lane = tid & 63, w = tid >> 6;
    float r0 = rois[i * 6 + 0], r1 = rois[i * 6 + 1], r2 = rois[i * 6 + 2];
    float r3 = rois[i * 6 + 3], r4 = rois[i * 6 + 4], th = rois[i * 6 + 5];
    int b = (int)r0;
    float cx = r1 * 0.125f, cy = r2 * 0.125f;
    float rw = fmaxf(r3 * 0.125f, 1.0f), rh = fmaxf(r4 * 0.125f, 1.0f);
    float bw = rw * (1.0f / 7.0f), bh = rh * (1.0f / 7.0f);
    float ct = cosf(th), st = sinf(th);
    const u16* fb = ft + (size_t)b * 65536 * CH;
    int coff = lane * 4;

    int start = w * 12 + (w > 0 ? 1 : 0);
    int cnt = (w == 0) ? 13 : 12;
    for (int bi = 0; bi < cnt; ++bi) {
        int bin = start + bi;
        int ph = bin / 7, pw = bin - ph * 7;
        float a0 = 0.f, a1 = 0.f, a2 = 0.f, a3 = 0.f;
#pragma unroll
        for (int s = 0; s < 4; ++s) {
            int sy = s >> 1, sx2 = s & 1;
            float yy = -rh * 0.5f + ((float)ph + ((float)sy + 0.5f) * 0.5f) * bh;
            float xx = -rw * 0.5f + ((float)pw + ((float)sx2 + 0.5f) * 0.5f) * bw;
            float xs = xx * ct - yy * st + cx;
            float ys = xx * st + yy * ct + cy;
            bool valid = (ys > -1.0f) && (ys < 256.0f) && (xs > -1.0f) && (xs < 256.0f);
            float ysc = fminf(fmaxf(ys, 0.f), 255.f);
            float xsc = fminf(fmaxf(xs, 0.f), 255.f);
            int yl = (int)floorf(ysc), xl = (int)floorf(xsc);
            int yh = min(yl + 1, 255), xh = min(xl + 1, 255);
            float ly = ysc - (float)yl, lx = xsc - (float)xl;
            float hy = 1.f - ly, hx = 1.f - lx;
            float w11 = hy * hx, w12 = hy * lx, w21 = ly * hx, w22 = ly * lx;
            if (!valid) { w11 = w12 = w21 = w22 = 0.f; }
            uint2 v11 = *(const uint2*)(fb + (((size_t)yl * 256 + xl) << 8) + coff);
            uint2 v12 = *(const uint2*)(fb + (((size_t)yl * 256 + xh) << 8) + coff);
            uint2 v21 = *(const uint2*)(fb + (((size_t)yh * 256 + xl) << 8) + coff);
            uint2 v22 = *(const uint2*)(fb + (((size_t)yh * 256 + xh) << 8) + coff);
            a0 += w11 * bf_lo(v11.x) + w12 * bf_lo(v12.x) + w21 * bf_lo(v21.x) + w22 * bf_lo(v22.x);
            a1 += w11 * bf_hi(v11.x) + w12 * bf_hi(v12.x) + w21 * bf_hi(v21.x) + w22 * bf_hi(v22.x);
            a2 += w11 * bf_lo(v11.y) + w12 * bf_lo(v12.y) + w21 * bf_lo(v21.y) + w22 * bf_lo(v22.y);
            a3 += w11 * bf_hi(v11.y) + w12 * bf_hi(v12.y) + w21 * bf_hi(v21.y) + w22 * bf_hi(v22.y);
        }
        uint2 o;
        o.x = (u32)f2b(a0 * 0.25f) | ((u32)f2b(a1 * 0.25f) << 16);
        o.y = (u32)f2b(a2 * 0.25f) | ((u32)f2b(a3 * 0.25f) << 16);
        *(uint2*)(sbuf + bin * 260 + coff) = o;
    }
    __syncthreads();
    // write flat[i][c*49+bin], 4 elems/thread/iter, coalesced uint2 stores
    uint2* fl = (uint2*)(flat + (size_t)i * KDIM);
#pragma unroll 1
    for (int k = tid; k < 3136; k += 256) {
        int e = k * 4;
        int c = e / 49, bn = e - c * 49;
        u16 r0_ = sbuf[bn * 260 + c]; if (++bn == 49) { bn = 0; ++c; }
        u16 r1_ = sbuf[bn * 260 + c]; if (++bn == 49) { bn = 0; ++c; }
        u16 r2_ = sbuf[bn * 260 + c]; if (++bn == 49) { bn = 0; ++c; }
        u16 r3_ = sbuf[bn * 260 + c];
        uint2 o;
        o.x = (u32)r0_ | ((u32)r1_ << 16);
        o.y = (u32)r2_ | ((u32)r3_ << 16);
        fl[k] = o;
    }
}

// ---------------- GEMM1: flat[1024,12544]bf16 @ w1t[1024,12544]^T -> part fp32 ----------------
// 256x256 tile, 8 waves (2Mx4N), BK=64, KSPLIT=14 (K-run = 14*64 = 896 exactly).
// 2-phase double-buffer: prefetch slice s+1 via global_load_lds during MFMA on s;
// counted s_waitcnt vmcnt(8) keeps the prefetch in flight across the barrier.
// XOR-8 swizzle applied on the GLOBAL side (global_load_lds dest must be linear).
__global__ __launch_bounds__(512) void gemm1(const u16* __restrict__ A,
                                             const u16* __restrict__ Bt,
                                             float* __restrict__ part) {
    const int K = KDIM;
    int nb = blockIdx.x, mb = blockIdx.y, ks = blockIdx.z;
    const int steps = 14;
    int kbase = ks * 896;
    __shared__ __align__(16) u16 As[2][256 * 64];   // 64KB
    __shared__ __align__(16) u16 Bs[2][256 * 64];   // 64KB
    int tid = threadIdx.x;
    int lane = tid & 63, w = tid >> 6;   // w 0..7
    int wm = w >> 2, wn = w & 3;         // wave grid 2M x 4N; wave tile 128x64
    f32x4 acc[8][4] = {};
    const u16* Ab = A + (size_t)(mb * 256) * K;
    const u16* Bb = Bt + (size_t)(nb * 256) * K;

    auto stage = [&](int buf, int kk) {
#pragma unroll
        for (int j = 0; j < 4; ++j) {
            int c = w * 4 + j;                 // 0..31
            int cid = c * 64 + lane;           // 0..2047
            int row = cid >> 3, pq = cid & 7;  // row 0..255
            int q = pq ^ (row & 7);            // global-side swizzle
            async16(Ab + (size_t)row * K + kk + q * 8, &As[buf][c * 512 + lane * 8]);
            async16(Bb + (size_t)row * K + kk + q * 8, &Bs[buf][c * 512 + lane * 8]);
        }
    };

    stage(0, kbase);
    int cur = 0;
    for (int s = 0; s < steps; ++s) {
        if (s + 1 < steps) {
            stage(cur ^ 1, kbase + (s + 1) * 64);            // 8 new loads in flight
            asm volatile("s_waitcnt vmcnt(8)" ::: "memory"); // own cur-buffer loads done
        } else {
            asm volatile("s_waitcnt vmcnt(0)" ::: "memory");
        }
        __builtin_amdgcn_s_barrier();                        // all waves' cur-buffer done
        const u16* Asb = &As[cur][0];
        const u16* Bsb = &Bs[cur][0];
#pragma unroll
        for (int kh = 0; kh < 2; ++kh) {
            short8 af[8], bf[4];
            int q = kh * 4 + (lane >> 4);
#pragma unroll
            for (int t = 0; t < 8; ++t) {
                int r = wm * 128 + t * 16 + (lane & 15);
                int pq = q ^ (r & 7);
                af[t] = *(const short8*)(Asb + r * 64 + pq * 8);
            }
#pragma unroll
            for (int t = 0; t < 4; ++t) {
                int rb = wn * 64 + t * 16 + (lane & 15);
                int pqb = q ^ (rb & 7);
                bf[t] = *(const short8*)(Bsb + rb * 64 + pqb * 8);
            }
#pragma unroll
            for (int mt = 0; mt < 8; ++mt)
#pragma unroll
                for (int nt = 0; nt < 4; ++nt)
                    acc[mt][nt] = __builtin_amdgcn_mfma_f32_16x16x32_bf16(af[mt], bf[nt], acc[mt][nt], 0, 0, 0);
        }
        __builtin_amdgcn_s_barrier();                        // reads of cur done before overwrite
        cur ^= 1;
    }
    float* P = part + (size_t)ks * NROI * NHID;
    int m_base = mb * 256 + wm * 128, n_base = nb * 256 + wn * 64;
#pragma unroll
    for (int mt = 0; mt < 8; ++mt)
#pragma unroll
        for (int nt = 0; nt < 4; ++nt)
#pragma unroll
            for (int i = 0; i < 4; ++i) {
                int m = m_base + mt * 16 + (lane >> 4) * 4 + i;
                int n = n_base + nt * 16 + (lane & 15);
                P[(size_t)m * NHID + n] = acc[mt][nt][i];
            }
}

// ---------------- fused: split-K reduce + bias + relu + GEMM2 + sigmoid + apply ----------------
__global__ __launch_bounds__(256) void gemm2_apply(const float* __restrict__ part,
                                                   const float* __restrict__ b1,
                                                   const float* __restrict__ w2t,
                                                   const float* __restrict__ b2,
                                                   const u16* __restrict__ flat,
                                                   float* __restrict__ out) {
    __shared__ __align__(16) float hrow[NHID];
    __shared__ float partial[256];
    __shared__ float mrow[49];
    int i = blockIdx.x;
    int tid = threadIdx.x;
    // reduce split-K partials for this roi's hid row + bias + relu, into LDS
    {
        float4 s = ((const float4*)b1)[tid];
        size_t base = (size_t)i * 256 + tid;   // float4 index within one K-slice
#pragma unroll
        for (int j = 0; j < KSPLIT; ++j) {
            float4 p = ((const float4*)part)[(size_t)j * 262144 + base];
            s.x += p.x; s.y += p.y; s.z += p.z; s.w += p.w;
        }
        float4 r;
        r.x = fmaxf(s.x, 0.f); r.y = fmaxf(s.y, 0.f);
        r.z = fmaxf(s.z, 0.f); r.w = fmaxf(s.w, 0.f);
        ((float4*)hrow)[tid] = r;
    }
    __syncthreads();
    float p = 0.f;
    if (tid < 245) {
        int j = tid / 5, kc = tid - (tid / 5) * 5;
        int k0 = (256 * kc) / 5, k1 = (256 * (kc + 1)) / 5;   // float4 chunks
        const float4* wv = (const float4*)(w2t + (size_t)j * NHID);
        const float4* hv = (const float4*)hrow;
        for (int k = k0; k < k1; ++k) {
            float4 a = hv[k], b = wv[k];
            p += a.x * b.x + a.y * b.y + a.z * b.z + a.w * b.w;
        }
    }
    partial[tid] = p;
    __syncthreads();
    if (tid < 49) {
        float s = b2[tid];
#pragma unroll
        for (int q = 0; q < 5; ++q) s += partial[tid * 5 + q];
        mrow[tid] = 1.f / (1.f + expf(-s));
    }
    __syncthreads();
    const uint2* fl = (const uint2*)(flat + (size_t)i * KDIM);
    float4* op = (float4*)(out + (size_t)i * KDIM);
#pragma unroll 1
    for (int idx = tid; idx < 3136; idx += 256) {
        uint2 v = fl[idx];
        int e = idx * 4;
        int pp = e - (e / 49) * 49;
        float4 r;
        r.x = bf_lo(v.x) * mrow[pp]; if (++pp == 49) pp = 0;
        r.y = bf_hi(v.x) * mrow[pp]; if (++pp == 49) pp = 0;
        r.z = bf_lo(v.y) * mrow[pp]; if (++pp == 49) pp = 0;
        r.w = bf_hi(v.y) * mrow[pp];
        op[idx] = r;
    }
}

extern "C" void kernel_launch(void* const* d_in, const int* in_sizes, int n_in,
                              void* d_out, int out_size, void* d_ws, size_t ws_size,
                              hipStream_t stream) {
    const float* features = (const float*)d_in[0];
    const float* rois     = (const float*)d_in[1];
    const float* w1       = (const float*)d_in[2];
    const float* b1       = (const float*)d_in[3];
    const float* w2       = (const float*)d_in[4];
    const float* b2       = (const float*)d_in[5];
    float* out = (float*)d_out;
    char* ws = (char*)d_ws;

    u16* featT  = (u16*)(ws);                      // 67,108,864
    u16* flat   = (u16*)(ws + 67108864);           // 25,690,112
    u16* w1t    = (u16*)(ws + 92798976);           // 25,690,112
    float* part = (float*)(ws + 118489088);        // 58,720,256 (KSPLIT=14)
    float* w2t  = (float*)(ws + 177209344);        // 200,704

    prep<<<5233, 256, 0, stream>>>(features, w1, w2, featT, w1t, w2t);
    roi_align<<<NROI, 256, 0, stream>>>(featT, rois, flat);
    gemm1<<<dim3(4, 4, KSPLIT), 512, 0, stream>>>(flat, w1t, part);
    gemm2_apply<<<NROI, 256, 0, stream>>>(part, b1, w2t, b2, flat, out);
}